// Round 1
// baseline (579.311 us; speedup 1.0000x reference)
//
#include <hip/hip_runtime.h>

typedef unsigned short u16;
typedef unsigned int u32;
typedef __bf16 bf16x8 __attribute__((ext_vector_type(8)));
typedef float f32x4 __attribute__((ext_vector_type(4)));

#define SCALE 0.07905694150420949f  // (128+32)^-0.5

__device__ __forceinline__ float bf2f(u16 h) { return __uint_as_float(((u32)h) << 16); }
__device__ __forceinline__ u16 f2bf(float f) {
  u32 u = __float_as_uint(f);
  u += 0x7fffu + ((u >> 16) & 1u);
  return (u16)(u >> 16);
}
__device__ __forceinline__ bf16x8 ldfrag(const u16* p) {
  int4 t = *reinterpret_cast<const int4*>(p);
  return __builtin_bit_cast(bf16x8, t);
}

// ---------------- f32 -> bf16 convert ----------------
__global__ void conv_f32_bf16(const float* __restrict__ in, u16* __restrict__ out, int n) {
  for (int i = blockIdx.x * blockDim.x + threadIdx.x; i < n; i += gridDim.x * blockDim.x)
    out[i] = f2bf(in[i]);
}

// ---------------- GEMM: C[M,N] = A[M,K](bf16) @ B[N,K](bf16)^T ----------------
// 128x128 tile, BK=64, 4 waves (2x2), each wave 64x64 (4x4 of 16x16 frags)
template <int OUT_BF16>
__global__ __launch_bounds__(256) void gemm_bt(const u16* __restrict__ A,
                                               const u16* __restrict__ Bw,
                                               void* __restrict__ Cv,
                                               int M, int N, int K) {
  __shared__ __align__(16) u16 As[128][64];
  __shared__ __align__(16) u16 Bs[128][64];
  const int tid = threadIdx.x;
  const int nbn = N >> 7;
  const int bm = blockIdx.x / nbn, bn = blockIdx.x % nbn;
  const int row0 = bm << 7, col0 = bn << 7;
  const int lane = tid & 63, w = tid >> 6;
  const int lg = lane >> 4, lr = lane & 15;
  const int wr = w >> 1, wc = w & 1;
  f32x4 acc[4][4] = {};
  for (int k0 = 0; k0 < K; k0 += 64) {
    for (int i = tid; i < 1024; i += 256) {
      int r = i >> 3, c = (i & 7) << 3;
      *reinterpret_cast<int4*>(&As[r][c]) =
          *reinterpret_cast<const int4*>(&A[(size_t)(row0 + r) * K + k0 + c]);
      *reinterpret_cast<int4*>(&Bs[r][c]) =
          *reinterpret_cast<const int4*>(&Bw[(size_t)(col0 + r) * K + k0 + c]);
    }
    __syncthreads();
#pragma unroll
    for (int kk = 0; kk < 2; ++kk) {
      bf16x8 af[4], bv[4];
#pragma unroll
      for (int m = 0; m < 4; ++m) af[m] = ldfrag(&As[wr * 64 + m * 16 + lr][kk * 32 + lg * 8]);
#pragma unroll
      for (int n = 0; n < 4; ++n) bv[n] = ldfrag(&Bs[wc * 64 + n * 16 + lr][kk * 32 + lg * 8]);
#pragma unroll
      for (int m = 0; m < 4; ++m)
#pragma unroll
        for (int n = 0; n < 4; ++n)
          acc[m][n] = __builtin_amdgcn_mfma_f32_16x16x32_bf16(af[m], bv[n], acc[m][n], 0, 0, 0);
    }
    __syncthreads();
  }
#pragma unroll
  for (int m = 0; m < 4; ++m)
#pragma unroll
    for (int n = 0; n < 4; ++n)
#pragma unroll
      for (int r = 0; r < 4; ++r) {
        int row = row0 + wr * 64 + m * 16 + lg * 4 + r;
        int col = col0 + wc * 64 + n * 16 + lr;
        float v = acc[m][n][r];
        if (OUT_BF16)
          ((u16*)Cv)[(size_t)row * N + col] = f2bf(v);
        else
          ((float*)Cv)[(size_t)row * N + col] = v;
      }
}

// ---------------- postprocess: RMSNorm heads + behavior embed concat + V transpose ----------------
// qkv: [B*S][3072] bf16 (cols: 0..2047 q, 2048..2559 k, 2560..3071 v)
// outputs: qcat [B][16][S][160], kcat [B][4][S][160], vt [B][4][128][S]  (all bf16)
__global__ __launch_bounds__(256) void postproc(
    const u16* __restrict__ qkv, const int* __restrict__ bidx,
    const float* __restrict__ qnw, const float* __restrict__ knw,
    const float* __restrict__ qbe_t, const float* __restrict__ kbe_t,
    const float* __restrict__ qbn, const float* __restrict__ kbn,
    u16* __restrict__ qcat, u16* __restrict__ kcat, u16* __restrict__ vt) {
  const int tok = blockIdx.x;
  const int b = tok >> 11, s = tok & 2047;
  const int w = threadIdx.x >> 6, lane = threadIdx.x & 63;
  const int idx = bidx[tok];
  const u16* base = qkv + (size_t)tok * 3072;

  // --- q heads: 4 per wave ---
  for (int h = w; h < 16; h += 4) {
    float x0 = bf2f(base[h * 128 + 2 * lane]);
    float x1 = bf2f(base[h * 128 + 2 * lane + 1]);
    float ss = x0 * x0 + x1 * x1;
#pragma unroll
    for (int o = 32; o; o >>= 1) ss += __shfl_xor(ss, o);
    float rn = rsqrtf(ss * (1.f / 128.f) + 1e-6f);
    size_t ob = ((size_t)(b * 16 + h) * 2048 + s) * 160;
    qcat[ob + 2 * lane] = f2bf(x0 * rn * qnw[2 * lane]);
    qcat[ob + 2 * lane + 1] = f2bf(x1 * rn * qnw[2 * lane + 1]);
    if (lane < 32) {
      float e = qbe_t[idx * 512 + h * 32 + lane];
      float s2 = e * e;
#pragma unroll
      for (int o = 16; o; o >>= 1) s2 += __shfl_xor(s2, o);
      qcat[ob + 128 + lane] = f2bf(e * rsqrtf(s2 * (1.f / 32.f) + 1e-6f) * qbn[lane]);
    }
  }
  // --- k head + v transpose: kv = wave id ---
  {
    const int kv = w;
    float x0 = bf2f(base[2048 + kv * 128 + 2 * lane]);
    float x1 = bf2f(base[2048 + kv * 128 + 2 * lane + 1]);
    float ss = x0 * x0 + x1 * x1;
#pragma unroll
    for (int o = 32; o; o >>= 1) ss += __shfl_xor(ss, o);
    float rn = rsqrtf(ss * (1.f / 128.f) + 1e-6f);
    size_t ob = ((size_t)(b * 4 + kv) * 2048 + s) * 160;
    kcat[ob + 2 * lane] = f2bf(x0 * rn * knw[2 * lane]);
    kcat[ob + 2 * lane + 1] = f2bf(x1 * rn * knw[2 * lane + 1]);
    if (lane < 32) {
      float e = kbe_t[idx * 128 + kv * 32 + lane];
      float s2 = e * e;
#pragma unroll
      for (int o = 16; o; o >>= 1) s2 += __shfl_xor(s2, o);
      kcat[ob + 128 + lane] = f2bf(e * rsqrtf(s2 * (1.f / 32.f) + 1e-6f) * kbn[lane]);
    }
    size_t vb = (size_t)(b * 4 + kv) * 128 * 2048;
    vt[vb + (size_t)lane * 2048 + s] = base[2560 + kv * 128 + lane];
    vt[vb + (size_t)(lane + 64) * 2048 + s] = base[2560 + kv * 128 + 64 + lane];
  }
}

// ---------------- flash attention (causal, GQA 4:1) ----------------
// 1 wave per block; block = (b,h,qblk of 16 rows). Key tiles of 32.
__global__ __launch_bounds__(64) void attn(const u16* __restrict__ qcat,
                                           const u16* __restrict__ kcat,
                                           const u16* __restrict__ vt,
                                           u16* __restrict__ aout) {
  __shared__ __align__(16) u16 p_lds[16][32];
  const int blk = blockIdx.x;
  const int qb = blk & 127;
  const int h = (blk >> 7) & 15;
  const int b = blk >> 11;
  const int kvh = h >> 2;
  const int lane = threadIdx.x;
  const int lg = lane >> 4, lr = lane & 15;

  const u16* qp = qcat + ((size_t)(b * 16 + h) * 2048 + qb * 16) * 160;
  bf16x8 qf[5];
#pragma unroll
  for (int c = 0; c < 5; ++c) qf[c] = ldfrag(qp + lr * 160 + c * 32 + lg * 8);

  const u16* kbp = kcat + (size_t)(b * 4 + kvh) * 2048 * 160;
  const u16* vbp = vt + (size_t)(b * 4 + kvh) * 128 * 2048;

  float mrow[4] = {-INFINITY, -INFINITY, -INFINITY, -INFINITY};
  float lsum[4] = {0.f, 0.f, 0.f, 0.f};
  f32x4 acc_o[8] = {};
  const int nkt = (qb * 16 + 15) / 32 + 1;

  for (int kt = 0; kt < nkt; ++kt) {
    f32x4 s0 = {}, s1 = {};
    const u16* kp = kbp + (size_t)(kt * 32) * 160;
#pragma unroll
    for (int c = 0; c < 5; ++c) {
      bf16x8 k0 = ldfrag(kp + lr * 160 + c * 32 + lg * 8);
      bf16x8 k1 = ldfrag(kp + (16 + lr) * 160 + c * 32 + lg * 8);
      s0 = __builtin_amdgcn_mfma_f32_16x16x32_bf16(qf[c], k0, s0, 0, 0, 0);
      s1 = __builtin_amdgcn_mfma_f32_16x16x32_bf16(qf[c], k1, s1, 0, 0, 0);
    }
    float corr[4];
#pragma unroll
    for (int r = 0; r < 4; ++r) {
      int qpos = qb * 16 + lg * 4 + r;
      float v0 = s0[r] * SCALE, v1 = s1[r] * SCALE;
      if (kt * 32 + lr > qpos) v0 = -INFINITY;
      if (kt * 32 + 16 + lr > qpos) v1 = -INFINITY;
      float mx = fmaxf(v0, v1);
#pragma unroll
      for (int o = 1; o < 16; o <<= 1) mx = fmaxf(mx, __shfl_xor(mx, o));
      float mn = fmaxf(mrow[r], mx);
      corr[r] = __expf(mrow[r] - mn);
      float p0 = __expf(v0 - mn), p1 = __expf(v1 - mn);
      float rs = p0 + p1;
#pragma unroll
      for (int o = 1; o < 16; o <<= 1) rs += __shfl_xor(rs, o);
      lsum[r] = lsum[r] * corr[r] + rs;
      mrow[r] = mn;
      p_lds[lg * 4 + r][lr] = f2bf(p0);
      p_lds[lg * 4 + r][16 + lr] = f2bf(p1);
    }
#pragma unroll
    for (int dt = 0; dt < 8; ++dt)
#pragma unroll
      for (int r = 0; r < 4; ++r) acc_o[dt][r] *= corr[r];
    __syncthreads();
    bf16x8 pf = ldfrag(&p_lds[lr][lg * 8]);
#pragma unroll
    for (int dt = 0; dt < 8; ++dt) {
      bf16x8 vf = ldfrag(vbp + (size_t)(dt * 16 + lr) * 2048 + kt * 32 + lg * 8);
      acc_o[dt] = __builtin_amdgcn_mfma_f32_16x16x32_bf16(pf, vf, acc_o[dt], 0, 0, 0);
    }
    __syncthreads();
  }
#pragma unroll
  for (int dt = 0; dt < 8; ++dt)
#pragma unroll
    for (int r = 0; r < 4; ++r) {
      int row = qb * 16 + lg * 4 + r;
      aout[((size_t)(b * 2048 + row) * 16 + h) * 128 + dt * 16 + lr] =
          f2bf(acc_o[dt][r] / lsum[r]);
    }
}

extern "C" void kernel_launch(void* const* d_in, const int* in_sizes, int n_in,
                              void* d_out, int out_size, void* d_ws, size_t ws_size,
                              hipStream_t stream) {
  const float* hs = (const float*)d_in[0];
  const int* bidx = (const int*)d_in[1];
  const float* qw = (const float*)d_in[2];
  const float* kw = (const float*)d_in[3];
  const float* vw = (const float*)d_in[4];
  const float* ow = (const float*)d_in[5];
  const float* qnw = (const float*)d_in[6];
  const float* knw = (const float*)d_in[7];
  const float* qbe_t = (const float*)d_in[8];
  const float* kbe_t = (const float*)d_in[9];
  const float* qbn = (const float*)d_in[10];
  const float* kbn = (const float*)d_in[11];
  float* out = (float*)d_out;

  u16* ws = (u16*)d_ws;
  u16* hs_bf = ws;                       // 4096*2048          = 8388608
  u16* wqkv = hs_bf + 8388608;           // 3072*2048          = 6291456
  u16* ow_bf = wqkv + 6291456;           // 2048*2048          = 4194304
  u16* qkv = ow_bf + 4194304;            // 4096*3072          = 12582912
  u16* qcat = qkv + 12582912;            // 2*16*2048*160      = 10485760
  u16* kcat = qcat + 10485760;           // 2*4*2048*160       = 2621440
  u16* vt = kcat + 2621440;              // 2*4*128*2048       = 2097152
  u16* attn_o = vt + 2097152;            // 4096*2048          = 8388608
  // total: 110,100,480 bytes

  // 1) converts
  conv_f32_bf16<<<4096, 256, 0, stream>>>(hs, hs_bf, 8388608);
  conv_f32_bf16<<<2048, 256, 0, stream>>>(qw, wqkv, 4194304);
  conv_f32_bf16<<<1024, 256, 0, stream>>>(kw, wqkv + 4194304, 1048576);
  conv_f32_bf16<<<1024, 256, 0, stream>>>(vw, wqkv + 5242880, 1048576);
  conv_f32_bf16<<<2048, 256, 0, stream>>>(ow, ow_bf, 4194304);

  // 2) fused QKV GEMM: [4096 x 3072] = hs_bf[4096x2048] @ wqkv[3072x2048]^T
  gemm_bt<1><<<dim3((4096 / 128) * (3072 / 128)), 256, 0, stream>>>(
      hs_bf, wqkv, (void*)qkv, 4096, 3072, 2048);

  // 3) per-head RMSNorm + behavior embeds + V transpose
  postproc<<<4096, 256, 0, stream>>>(qkv, bidx, qnw, knw, qbe_t, kbe_t, qbn, kbn,
                                     qcat, kcat, vt);

  // 4) causal flash attention
  attn<<<4096, 64, 0, stream>>>(qcat, kcat, vt, attn_o);

  // 5) O projection: out[4096x2048] = attn_o @ ow^T (f32 out)
  gemm_bt<0><<<dim3((4096 / 128) * (2048 / 128)), 256, 0, stream>>>(
      attn_o, ow_bf, (void*)d_out, 4096, 2048, 2048);
}